// Round 16
// baseline (53.141 us; speedup 1.0000x reference)
//
#include <hip/hip_runtime.h>
#include <hip/hip_bf16.h>
#include <cstdint>
#include <cstddef>

typedef __attribute__((ext_vector_type(8))) short bf16x8;
typedef __attribute__((ext_vector_type(4))) float f32x4;
typedef __attribute__((ext_vector_type(4))) unsigned int u32x4;

#define T_DIM 2048
#define C_DIM 1024
#define B_DIM 8
#define NEG_BIG (-3.0e38f)
#define QSCALE 0.18033688011112042f   // (1/8) * log2(e): softmax in exp2 domain

__device__ __forceinline__ unsigned short f2bf(float f) {
  union { __hip_bfloat16 h; unsigned short u; } cv;
  cv.h = __float2bfloat16(f);
  return cv.u;
}
__device__ __forceinline__ f32x4 mfma16(bf16x8 a, bf16x8 b, f32x4 c) {
  return __builtin_amdgcn_mfma_f32_16x16x32_bf16(a, b, c, 0, 0, 0);
}

// ---------------------------------------------------------------------------
// prep_w: W [1024][64] f32 -> Wt [3][64][1024] bf16 (transposed; Wq scaled by
// (1/8)*log2e so softmax runs in exp2 domain). Unchanged.
// ---------------------------------------------------------------------------
__global__ __launch_bounds__(256) void prep_w(
    const float* __restrict__ Wq, const float* __restrict__ Wk,
    const float* __restrict__ Wv, unsigned short* __restrict__ Wt)
{
  const int mtx = blockIdx.x >> 4;
  const int k0  = (blockIdx.x & 15) * 64;
  const float* W = (mtx == 0) ? Wq : ((mtx == 1) ? Wk : Wv);
  const float scale = (mtx == 0) ? QSCALE : 1.0f;
  __shared__ float Ws[64][65];
  const int t = threadIdx.x;
#pragma unroll
  for (int j = 0; j < 4; ++j) {
    int r = (t >> 4) + 16 * j;
    int c = (t & 15) * 4;
    union { float4 f4; float f[4]; } uv;
    uv.f4 = *(const float4*)&W[(size_t)(k0 + r) * 64 + c];
#pragma unroll
    for (int jj = 0; jj < 4; ++jj) Ws[c + jj][r] = uv.f[jj] * scale;
  }
  __syncthreads();
#pragma unroll
  for (int q = 0; q < 2; ++q) {
    int g_ = t + 256 * q;
    int d  = g_ >> 3;
    int ko = (g_ & 7) * 8;
    union { unsigned short u[8]; u32x4 v; } pk;
#pragma unroll
    for (int jj = 0; jj < 8; ++jj) pk.u[jj] = f2bf(Ws[d][ko + jj]);
    *(u32x4*)&Wt[((size_t)mtx * 64 + d) * C_DIM + k0 + ko] = pk.v;
  }
}

// ---------------------------------------------------------------------------
// qkv_proj_mfma: round-12 pipelined version (512 x 32 rows). Unchanged.
// ---------------------------------------------------------------------------
__global__ __launch_bounds__(256) void qkv_proj_mfma(
    const float* __restrict__ x,
    const unsigned short* __restrict__ Wt,
    const float* __restrict__ bq, const float* __restrict__ bk, const float* __restrict__ bv,
    unsigned short* __restrict__ Qb, unsigned short* __restrict__ Kb,
    unsigned short* __restrict__ VTb)
{
  __shared__ __align__(16) short Xs[2][32 * 64];
  __shared__ __align__(16) short Wsb[2][3 * 64 * 64];
  __shared__ __align__(16) unsigned short VTs[64 * 40];

  const int tid = threadIdx.x;
  const int wv = tid >> 6, lane = tid & 63, g = lane >> 4, ln15 = lane & 15;
  const size_t m0 = (size_t)blockIdx.x * 32;

  f32x4 acc[2][3];
#pragma unroll
  for (int mt = 0; mt < 2; ++mt)
#pragma unroll
    for (int j = 0; j < 3; ++j) acc[mt][j] = (f32x4){0.f, 0.f, 0.f, 0.f};

  float4 xA[2], xB[2];
  u32x4 wr[6];

  auto issueX = [&](float4 (&xr)[2], int kt) {
    if (kt >= 16) return;
#pragma unroll
    for (int q = 0; q < 2; ++q) {
      int g_ = tid + 256 * q;
      int r = g_ >> 4, c4 = (g_ & 15) * 4;
      xr[q] = *(const float4*)&x[(m0 + r) * C_DIM + kt * 64 + c4];
    }
  };
  auto issueW = [&](int kt) {
    if (kt >= 16) return;
#pragma unroll
    for (int mt = 0; mt < 3; ++mt)
#pragma unroll
      for (int q = 0; q < 2; ++q) {
        int g_ = tid + 256 * q;
        int d = g_ >> 3, ko = (g_ & 7) * 8;
        wr[mt * 2 + q] = *(const u32x4*)&Wt[((size_t)mt * 64 + d) * C_DIM + kt * 64 + ko];
      }
  };
  auto writeXb = [&](int nb, const float4 (&xr)[2]) {
#pragma unroll
    for (int q = 0; q < 2; ++q) {
      int g_ = tid + 256 * q;
      int r = g_ >> 4, c4 = (g_ & 15) * 4;
      const float* f = (const float*)&xr[q];
      union { unsigned short u[4]; unsigned long long ll; } pk;
#pragma unroll
      for (int jj = 0; jj < 4; ++jj) pk.u[jj] = f2bf(f[jj]);
      *(unsigned long long*)((char*)Xs[nb] + r * 128 + ((c4 * 2) ^ ((r & 7) << 4))) = pk.ll;
    }
  };
  auto writeWb = [&](int nb) {
#pragma unroll
    for (int mt = 0; mt < 3; ++mt)
#pragma unroll
      for (int q = 0; q < 2; ++q) {
        int g_ = tid + 256 * q;
        int d = g_ >> 3, ko = (g_ & 7) * 8;
        *(u32x4*)((char*)Wsb[nb] + mt * 8192 + d * 128 + ((ko * 2) ^ ((d & 7) << 4))) = wr[mt * 2 + q];
      }
  };
  auto compute = [&](int nb) {
#pragma unroll
    for (int kc = 0; kc < 2; ++kc) {
      bf16x8 a[2];
#pragma unroll
      for (int mt = 0; mt < 2; ++mt) {
        int xr = mt * 16 + ln15;
        a[mt] = *(const bf16x8*)((const char*)Xs[nb] + xr * 128 + ((kc * 64 + g * 16) ^ ((xr & 7) << 4)));
      }
#pragma unroll
      for (int j = 0; j < 3; ++j) {
        int ntg = wv * 3 + j;
        int mtx = ntg >> 2, nc = (ntg & 3) * 16;
        int wrow = nc + ln15;
        bf16x8 bb = *(const bf16x8*)((const char*)Wsb[nb] + mtx * 8192 + wrow * 128 + ((kc * 64 + g * 16) ^ ((wrow & 7) << 4)));
#pragma unroll
        for (int mt = 0; mt < 2; ++mt)
          acc[mt][j] = mfma16(a[mt], bb, acc[mt][j]);
      }
    }
  };

  issueX(xA, 0); issueW(0);
  writeXb(0, xA); writeWb(0);
  issueX(xB, 1);
  __syncthreads();

  for (int kt = 0; kt < 16; kt += 2) {
    issueW(kt + 1);
    issueX(xA, kt + 2);
    compute(0);
    if (kt + 1 < 16) { writeXb(1, xB); writeWb(1); }
    __syncthreads();
    if (kt + 1 < 16) {
      issueW(kt + 2);
      issueX(xB, kt + 3);
      compute(1);
      if (kt + 2 < 16) { writeXb(0, xA); writeWb(0); }
      __syncthreads();
    }
  }

#pragma unroll
  for (int j = 0; j < 3; ++j) {
    int ntg = wv * 3 + j;
    int mtx = ntg >> 2, nc = (ntg & 3) * 16;
    if (mtx < 2) {
      const float* bias = (mtx == 0) ? bq : bk;
      unsigned short* Out = (mtx == 0) ? Qb : Kb;
      float bvv = bias[nc + ln15] * ((mtx == 0) ? QSCALE : 1.0f);
#pragma unroll
      for (int mt = 0; mt < 2; ++mt)
#pragma unroll
        for (int i = 0; i < 4; ++i)
          Out[(m0 + mt * 16 + 4 * g + i) * 64 + nc + ln15] = f2bf(acc[mt][j][i] + bvv);
    } else {
      float bvv = bv[nc + ln15];
#pragma unroll
      for (int mt = 0; mt < 2; ++mt)
#pragma unroll
        for (int i = 0; i < 4; ++i)
          VTs[(nc + ln15) * 40 + mt * 16 + 4 * g + i] = f2bf(acc[mt][j][i] + bvv);
    }
  }
  __syncthreads();
  {
    int d = tid >> 2, t8 = (tid & 3) * 8;
    u32x4 v0 = *(const u32x4*)&VTs[d * 40 + t8];
    size_t b = m0 >> 11, tloc = m0 & 2047;
    *(u32x4*)&VTb[(b * 64 + d) * T_DIM + tloc + t8] = v0;
  }
}

// ---------------------------------------------------------------------------
// attn_flash: r15 kernel + K-fragment register double-buffer (named kA/kB,
// 2-unrolled). QK^T(n) consumes K loaded one iteration earlier; K(n+4)
// issues at phase start and has the full softmax+PV of iteration n to land.
// Occupancy is LDS-pinned at 2 blocks/CU, so (unlike r8) the +32 VGPR
// cannot reduce residency. Only change vs r15.
// ---------------------------------------------------------------------------
__global__ __launch_bounds__(256, 2) void attn_flash(
    const unsigned short* __restrict__ Qb,   // [B*T][64] (pre-scaled QSCALE)
    const unsigned short* __restrict__ Kb,   // [B*T][64]
    const unsigned short* __restrict__ VTb,  // [B][64][T]
    float* __restrict__ out)                 // [B*T][64] f32
{
  __shared__ __align__(16) short Ps[4][2 * 16 * 64];
  __shared__ __align__(16) float Zs[3][2][16 * 68];
  __shared__ float Ml[3][2][16][2];

  const int tid  = threadIdx.x;
  const int wv   = tid >> 6;
  const int lane = tid & 63;
  const int g    = lane >> 4;
  const int ln15 = lane & 15;

  const int qt = 63 - (blockIdx.x >> 3);
  const int b  = blockIdx.x & 7;
  const int r0 = qt * 32;
  const int ntiles = (qt >> 1) + 1;

  const size_t bT = (size_t)b * T_DIM;

  bf16x8 qa[2][2];
#pragma unroll
  for (int mt = 0; mt < 2; ++mt) {
    const unsigned short* qp = Qb + (bT + r0 + mt * 16 + ln15) * 64 + g * 8;
    qa[mt][0] = *(const bf16x8*)qp;
    qa[mt][1] = *(const bf16x8*)(qp + 32);
  }

  f32x4 acc[2][4];
#pragma unroll
  for (int mt = 0; mt < 2; ++mt)
#pragma unroll
    for (int dt = 0; dt < 4; ++dt) acc[mt][dt] = (f32x4){0.f, 0.f, 0.f, 0.f};
  float m_[2], l_[2];
#pragma unroll
  for (int mt = 0; mt < 2; ++mt) { m_[mt] = NEG_BIG; l_[mt] = 0.f; }

  char* myP = (char*)Ps[wv];

  auto loadK = [&](bf16x8 (&kf)[4][2], int it) {
    const int s0 = it * 64;
#pragma unroll
    for (int nt = 0; nt < 4; ++nt) {
      const unsigned short* kp = Kb + (bT + s0 + nt * 16 + ln15) * 64 + g * 8;
      kf[nt][0] = *(const bf16x8*)kp;
      kf[nt][1] = *(const bf16x8*)(kp + 32);
    }
  };
  auto loadV = [&](bf16x8 (&vf)[4][2], int it) {
    const int s0 = it * 64;
#pragma unroll
    for (int dt = 0; dt < 4; ++dt) {
      const unsigned short* vp = VTb + ((size_t)b * 64 + dt * 16 + ln15) * T_DIM + s0 + g * 8;
      vf[dt][0] = *(const bf16x8*)vp;
      vf[dt][1] = *(const bf16x8*)(vp + 32);
    }
  };
  auto step = [&](const bf16x8 (&kf)[4][2], const bf16x8 (&vf)[4][2], int it) {
    const int s0 = it * 64;
    f32x4 st[2][4];
    __builtin_amdgcn_s_setprio(1);
#pragma unroll
    for (int mt = 0; mt < 2; ++mt)
#pragma unroll
      for (int nt = 0; nt < 4; ++nt) {
        f32x4 a = (f32x4){0.f, 0.f, 0.f, 0.f};
        a = mfma16(kf[nt][0], qa[mt][0], a);
        a = mfma16(kf[nt][1], qa[mt][1], a);
        st[mt][nt] = a;
      }
    __builtin_amdgcn_s_setprio(0);
    if (s0 + 63 > r0) {
#pragma unroll
      for (int mt = 0; mt < 2; ++mt) {
        const int qg = r0 + mt * 16 + ln15;
#pragma unroll
        for (int nt = 0; nt < 4; ++nt) {
          const int kvb = s0 + nt * 16 + 4 * g;
#pragma unroll
          for (int i = 0; i < 4; ++i)
            if (kvb + i > qg) st[mt][nt][i] = NEG_BIG;
        }
      }
    }
#pragma unroll
    for (int mt = 0; mt < 2; ++mt) {
      f32x4 t4;
#pragma unroll
      for (int i = 0; i < 4; ++i)
        t4[i] = fmaxf(fmaxf(st[mt][0][i], st[mt][1][i]), fmaxf(st[mt][2][i], st[mt][3][i]));
      float mx = fmaxf(fmaxf(t4[0], t4[1]), fmaxf(t4[2], t4[3]));
      if (!__all((int)(mx <= m_[mt] + 8.0f))) {
        mx = fmaxf(mx, __shfl_xor(mx, 16));
        mx = fmaxf(mx, __shfl_xor(mx, 32));
        const float mn = fmaxf(m_[mt], mx);
        const float corr = exp2f(m_[mt] - mn);
        m_[mt] = mn;
        l_[mt] *= corr;
#pragma unroll
        for (int dt = 0; dt < 4; ++dt)
#pragma unroll
          for (int i = 0; i < 4; ++i)
            acc[mt][dt][i] *= corr;
      }
#pragma unroll
      for (int nt = 0; nt < 4; ++nt)
#pragma unroll
        for (int i = 0; i < 4; ++i)
          st[mt][nt][i] = exp2f(st[mt][nt][i] - m_[mt]);
      float ps = 0.f;
#pragma unroll
      for (int nt = 0; nt < 4; ++nt)
        ps += (st[mt][nt][0] + st[mt][nt][1]) + (st[mt][nt][2] + st[mt][nt][3]);
      l_[mt] += ps;
#pragma unroll
      for (int nt = 0; nt < 4; ++nt) {
        unsigned int lo_ = (unsigned int)f2bf(st[mt][nt][0]) | ((unsigned int)f2bf(st[mt][nt][1]) << 16);
        unsigned int hi_ = (unsigned int)f2bf(st[mt][nt][2]) | ((unsigned int)f2bf(st[mt][nt][3]) << 16);
        *(unsigned long long*)(myP + mt * 2048 + ln15 * 128 +
                               ((nt * 32 + g * 8) ^ ((ln15 & 7) << 4))) =
            ((unsigned long long)hi_ << 32) | lo_;
      }
    }
    bf16x8 pb[2][2];
#pragma unroll
    for (int mt = 0; mt < 2; ++mt)
#pragma unroll
      for (int kc = 0; kc < 2; ++kc)
        pb[mt][kc] = *(const bf16x8*)(myP + mt * 2048 + ln15 * 128 +
                                      ((kc * 64 + g * 16) ^ ((ln15 & 7) << 4)));
    __builtin_amdgcn_s_setprio(1);
#pragma unroll
    for (int mt = 0; mt < 2; ++mt)
#pragma unroll
      for (int dt = 0; dt < 4; ++dt) {
        acc[mt][dt] = mfma16(vf[dt][0], pb[mt][0], acc[mt][dt]);
        acc[mt][dt] = mfma16(vf[dt][1], pb[mt][1], acc[mt][dt]);
      }
    __builtin_amdgcn_s_setprio(0);
  };

  // K prefetched one wave-iteration (4 tiles) ahead; V issued at phase start.
  bf16x8 kA[4][2], kB[4][2], vf[4][2];
  if (wv < ntiles) loadK(kA, wv);
  for (int it = wv; it < ntiles; it += 8) {
    loadV(vf, it);
    if (it + 4 < ntiles) loadK(kB, it + 4);
    step(kA, vf, it);
    if (it + 4 < ntiles) {
      loadV(vf, it + 4);
      if (it + 8 < ntiles) loadK(kA, it + 8);
      step(kB, vf, it + 4);
    }
  }

  // finalize deferred l
#pragma unroll
  for (int mt = 0; mt < 2; ++mt) {
    l_[mt] += __shfl_xor(l_[mt], 16);
    l_[mt] += __shfl_xor(l_[mt], 32);
  }

  if (wv > 0) {
#pragma unroll
    for (int mt = 0; mt < 2; ++mt) {
#pragma unroll
      for (int dt = 0; dt < 4; ++dt)
        *(f32x4*)&Zs[wv - 1][mt][ln15 * 68 + dt * 16 + 4 * g] = acc[mt][dt];
      if (g == 0) {
        Ml[wv - 1][mt][ln15][0] = m_[mt];
        Ml[wv - 1][mt][ln15][1] = l_[mt];
      }
    }
  }
  __syncthreads();
  if (wv == 0) {
#pragma unroll
    for (int mt = 0; mt < 2; ++mt) {
      float mm = m_[mt];
#pragma unroll
      for (int w = 0; w < 3; ++w) mm = fmaxf(mm, Ml[w][mt][ln15][0]);
      const float e0 = exp2f(m_[mt] - mm);
      float lsum = l_[mt] * e0;
      float ew[3];
#pragma unroll
      for (int w = 0; w < 3; ++w) {
        ew[w] = exp2f(Ml[w][mt][ln15][0] - mm);
        lsum += Ml[w][mt][ln15][1] * ew[w];
      }
      const float inv = 1.0f / lsum;
      float* ob = out + (bT + r0 + mt * 16 + ln15) * 64;
#pragma unroll
      for (int dt = 0; dt < 4; ++dt) {
        f32x4 z;
#pragma unroll
        for (int i = 0; i < 4; ++i) {
          float zz = acc[mt][dt][i] * e0;
#pragma unroll
          for (int w = 0; w < 3; ++w)
            zz += Zs[w][mt][ln15 * 68 + dt * 16 + 4 * g + i] * ew[w];
          z[i] = zz * inv;
        }
        *(f32x4*)&ob[dt * 16 + 4 * g] = z;
      }
    }
  }
}

// ---------------------------------------------------------------------------
extern "C" void kernel_launch(void* const* d_in, const int* in_sizes, int n_in,
                              void* d_out, int out_size, void* d_ws, size_t ws_size,
                              hipStream_t stream)
{
  const float* x  = (const float*)d_in[0];
  const float* Wq = (const float*)d_in[1];
  const float* bq = (const float*)d_in[2];
  const float* Wk = (const float*)d_in[3];
  const float* bk = (const float*)d_in[4];
  const float* Wv = (const float*)d_in[5];
  const float* bv = (const float*)d_in[6];
  float* out = (float*)d_out;

  char* ws = (char*)d_ws;
  unsigned short* Wt  = (unsigned short*)(ws);                      // 384 KB
  unsigned short* Qb  = (unsigned short*)(ws + (1u << 19));         // 2 MB
  unsigned short* Kb  = (unsigned short*)(ws + (1u << 19) + (1u << 21));
  unsigned short* VTb = (unsigned short*)(ws + (1u << 19) + (2u << 21));

  prep_w<<<48, 256, 0, stream>>>(Wq, Wk, Wv, Wt);
  qkv_proj_mfma<<<512, 256, 0, stream>>>(x, Wt, bq, bk, bv, Qb, Kb, VTb);
  attn_flash<<<512, 256, 0, stream>>>(Qb, Kb, VTb, out);
}